// Round 1
// baseline (462.021 us; speedup 1.0000x reference)
//
#include <hip/hip_runtime.h>
#include <hip/hip_bf16.h>

// NT-Xent / InfoNCE loss. features [8192,1024] fp32 -> scalar fp32.
// Plan: normalize->bf16, fused MFMA GEMM (f f^T / T) + online row-logsumexp
// with self-mask + positive capture, then final merge/mean.

#define NROWS 8192
#define DDIM  1024
#define BHALF 4096            // positive index = row ^ BHALF
#define ISCALE 14.2857142857142857f  // 1/0.07

#define BM 128
#define BN 128
#define BK 64
#define NCHUNK 8
#define CHUNK_COLS (NROWS / NCHUNK)   // 1024
#define CTILES (CHUNK_COLS / BN)      // 8
#define KSTEPS (DDIM / BK)            // 16

typedef float f32x4 __attribute__((ext_vector_type(4)));
typedef short s16x8 __attribute__((ext_vector_type(8)));
typedef __bf16 bf16x8 __attribute__((ext_vector_type(8)));

// ---- MFMA signature hedge: builtin takes either short8 or bf16x8 ----
template <typename V>
__device__ auto mfma_sel(V a, V b, f32x4 c, int)
    -> decltype(__builtin_amdgcn_mfma_f32_16x16x32_bf16(a, b, c, 0, 0, 0)) {
  return __builtin_amdgcn_mfma_f32_16x16x32_bf16(a, b, c, 0, 0, 0);
}
template <typename V>
__device__ f32x4 mfma_sel(V a, V b, f32x4 c, long) {
  return __builtin_amdgcn_mfma_f32_16x16x32_bf16(
      __builtin_bit_cast(bf16x8, a), __builtin_bit_cast(bf16x8, b), c, 0, 0, 0);
}
__device__ inline f32x4 MFMA(s16x8 a, s16x8 b, f32x4 c) {
  return mfma_sel(a, b, c, 0);
}

__device__ inline unsigned short f2bf(float x) {
  unsigned int b = __builtin_bit_cast(unsigned int, x);
  b += 0x7FFFu + ((b >> 16) & 1u);   // RNE
  return (unsigned short)(b >> 16);
}

// ---------------- kernel 1: L2-normalize rows, write bf16 ----------------
__global__ void norm_kernel(const float* __restrict__ in,
                            unsigned short* __restrict__ out) {
  int row = blockIdx.x;
  int t = threadIdx.x;                      // 256 threads
  const float4* r4 = (const float4*)(in + (size_t)row * DDIM);
  float4 v = r4[t];
  float ss = v.x * v.x + v.y * v.y + v.z * v.z + v.w * v.w;
  #pragma unroll
  for (int m = 1; m < 64; m <<= 1) ss += __shfl_xor(ss, m, 64);
  __shared__ float red[4];
  if ((t & 63) == 0) red[t >> 6] = ss;
  __syncthreads();
  float inv = 1.0f / sqrtf(red[0] + red[1] + red[2] + red[3]);
  ushort4 o;
  o.x = f2bf(v.x * inv); o.y = f2bf(v.y * inv);
  o.z = f2bf(v.z * inv); o.w = f2bf(v.w * inv);
  ((ushort4*)(out + (size_t)row * DDIM))[t] = o;
}

// ---- staging: linear LDS dest (global_load_lds), swizzled global source ---
// LDS tile layout: 128 rows x 128 bytes; 16B slot s of row r holds
// k-elements c*8..c*8+7 where c = s ^ (r&7).  Read applies the same XOR.
__device__ inline void stage_tile(const unsigned short* __restrict__ f,
                                  unsigned short* lds, int row0, int kbase,
                                  int w, int lane) {
  #pragma unroll
  for (int i = 0; i < 4; ++i) {
    int q = w * 4 + i;                 // 16 wave-issues of 1024B per tile
    int r = q * 8 + (lane >> 3);
    int slot = lane & 7;
    int c = slot ^ (r & 7);
    const unsigned short* g = f + (size_t)(row0 + r) * DDIM + kbase + c * 8;
    __builtin_amdgcn_global_load_lds(
        (const __attribute__((address_space(1))) void*)g,
        (__attribute__((address_space(3))) void*)(lds + q * 512), 16, 0, 0);
  }
}

// ---------------- kernel 2: fused sim GEMM + online logsumexp -------------
__global__ __launch_bounds__(256)
void simloss_kernel(const unsigned short* __restrict__ f,
                    float* __restrict__ m_part, float* __restrict__ s_part,
                    float* __restrict__ pos_out) {
  __shared__ __align__(16) unsigned short As[BM * BK];  // 16 KB
  __shared__ __align__(16) unsigned short Bs[BN * BK];  // 16 KB

  int bid = blockIdx.x;
  int rt = bid / NCHUNK;
  int ch = bid % NCHUNK;
  int rowBase = rt * BM;
  int chunkBase = ch * CHUNK_COLS;

  int tid = threadIdx.x;
  int lane = tid & 63;
  int w = tid >> 6;        // 4 waves
  int wm = w >> 1, wn = w & 1;

  float m_run[16], s_run[16];
  #pragma unroll
  for (int i = 0; i < 16; ++i) { m_run[i] = -1e30f; s_run[i] = 0.f; }

  for (int ct = 0; ct < CTILES; ++ct) {
    int colBase = chunkBase + ct * BN;
    f32x4 acc[4][4];
    #pragma unroll
    for (int i = 0; i < 4; ++i)
      #pragma unroll
      for (int j = 0; j < 4; ++j) acc[i][j] = (f32x4){0.f, 0.f, 0.f, 0.f};

    for (int kt = 0; kt < KSTEPS; ++kt) {
      __syncthreads();                       // prior reads of As/Bs done
      stage_tile(f, As, rowBase, kt * BK, w, lane);
      stage_tile(f, Bs, colBase, kt * BK, w, lane);
      __syncthreads();                       // staged data visible (vmcnt drained)

      #pragma unroll
      for (int kk = 0; kk < 2; ++kk) {       // two K=32 sub-steps of BK=64
        s16x8 a[4], b[4];
        int cs = (lane >> 4) + kk * 4;       // 16B slot index of k-elems
        #pragma unroll
        for (int fm = 0; fm < 4; ++fm) {
          int r = wm * 64 + fm * 16 + (lane & 15);
          a[fm] = *(const s16x8*)((const char*)As + r * 128 + ((cs ^ (r & 7)) << 4));
        }
        #pragma unroll
        for (int fn = 0; fn < 4; ++fn) {
          int r = wn * 64 + fn * 16 + (lane & 15);
          b[fn] = *(const s16x8*)((const char*)Bs + r * 128 + ((cs ^ (r & 7)) << 4));
        }
        #pragma unroll
        for (int fm = 0; fm < 4; ++fm)
          #pragma unroll
          for (int fn = 0; fn < 4; ++fn)
            acc[fm][fn] = MFMA(a[fm], b[fn], acc[fm][fn]);
      }
    }

    // online logsumexp update for this 128x128 tile
    #pragma unroll
    for (int fm = 0; fm < 4; ++fm) {
      #pragma unroll
      for (int j = 0; j < 4; ++j) {
        int R = rowBase + wm * 64 + fm * 16 + ((lane >> 4) << 2) + j;
        float v[4];
        #pragma unroll
        for (int fn = 0; fn < 4; ++fn) {
          int C = colBase + wn * 64 + fn * 16 + (lane & 15);
          float x = acc[fm][fn][j] * ISCALE;
          if (C == R) x = -1e30f;                    // self-mask
          if (C == (R ^ BHALF)) pos_out[R] = x;      // positive capture
          v[fn] = x;
        }
        float mx = fmaxf(fmaxf(v[0], v[1]), fmaxf(v[2], v[3]));
        mx = fmaxf(mx, __shfl_xor(mx, 1, 64));
        mx = fmaxf(mx, __shfl_xor(mx, 2, 64));
        mx = fmaxf(mx, __shfl_xor(mx, 4, 64));
        mx = fmaxf(mx, __shfl_xor(mx, 8, 64));
        int idx = fm * 4 + j;
        float nm = fmaxf(m_run[idx], mx);
        float sum = __expf(v[0] - nm) + __expf(v[1] - nm) +
                    __expf(v[2] - nm) + __expf(v[3] - nm);
        sum += __shfl_xor(sum, 1, 64);
        sum += __shfl_xor(sum, 2, 64);
        sum += __shfl_xor(sum, 4, 64);
        sum += __shfl_xor(sum, 8, 64);
        s_run[idx] = s_run[idx] * __expf(m_run[idx] - nm) + sum;
        m_run[idx] = nm;
      }
    }
  }

  // write partials: 16 per row (8 chunks x 2 col-waves)
  if ((lane & 15) == 0) {
    #pragma unroll
    for (int fm = 0; fm < 4; ++fm) {
      #pragma unroll
      for (int j = 0; j < 4; ++j) {
        int R = rowBase + wm * 64 + fm * 16 + ((lane >> 4) << 2) + j;
        int pc = ch * 2 + wn;
        m_part[(size_t)R * 16 + pc] = m_run[fm * 4 + j];
        s_part[(size_t)R * 16 + pc] = s_run[fm * 4 + j];
      }
    }
  }
}

// ---------------- kernel 3: merge partials, mean ----------------
__global__ void finalize_kernel(const float* __restrict__ m_part,
                                const float* __restrict__ s_part,
                                const float* __restrict__ pos,
                                float* __restrict__ out) {
  int t = threadIdx.x;  // 1024 threads, single block
  float local = 0.f;
  for (int r = t; r < NROWS; r += 1024) {
    float M = -1e30f;
    #pragma unroll
    for (int k = 0; k < 16; ++k) M = fmaxf(M, m_part[r * 16 + k]);
    float S = 0.f;
    #pragma unroll
    for (int k = 0; k < 16; ++k)
      S += s_part[r * 16 + k] * __expf(m_part[r * 16 + k] - M);
    local += (M + logf(S)) - pos[r];
  }
  #pragma unroll
  for (int m = 1; m < 64; m <<= 1) local += __shfl_xor(local, m, 64);
  __shared__ float red[16];
  if ((t & 63) == 0) red[t >> 6] = local;
  __syncthreads();
  if (t == 0) {
    float tot = 0.f;
    for (int i = 0; i < 16; ++i) tot += red[i];
    out[0] = tot / (float)NROWS;
  }
}

extern "C" void kernel_launch(void* const* d_in, const int* in_sizes, int n_in,
                              void* d_out, int out_size, void* d_ws,
                              size_t ws_size, hipStream_t stream) {
  const float* feats = (const float*)d_in[0];
  char* ws = (char*)d_ws;
  unsigned short* fbf = (unsigned short*)ws;                      // 16 MB
  float* m_part = (float*)(ws + (size_t)NROWS * DDIM * 2);        // 512 KB
  float* s_part = (float*)((char*)m_part + (size_t)NROWS * 16 * 4);
  float* pos    = (float*)((char*)s_part + (size_t)NROWS * 16 * 4);
  float* out = (float*)d_out;

  norm_kernel<<<NROWS, 256, 0, stream>>>(feats, fbf);
  simloss_kernel<<<(NROWS / BM) * NCHUNK, 256, 0, stream>>>(fbf, m_part,
                                                            s_part, pos);
  finalize_kernel<<<1, 1024, 0, stream>>>(m_part, s_part, pos, out);
}

// Round 2
// 217.515 us; speedup vs baseline: 2.1241x; 2.1241x over previous
//
#include <hip/hip_runtime.h>
#include <hip/hip_bf16.h>

// NT-Xent / InfoNCE loss. features [8192,1024] fp32 -> scalar fp32.
// normalize->bf16, fused MFMA GEMM (f f^T / T) + fixed-max logsumexp
// (rows unit-norm => logits <= 1/T, so max is a compile-time constant),
// then split finalize.

#define NROWS 8192
#define DDIM  1024
#define BHALF 4096            // positive index = row ^ BHALF
#define ISCALE 14.2857142857142857f  // 1/0.07 == fixed logsumexp max M0

#define BM 128
#define BN 128
#define BK 64
#define NCHUNK 16
#define CHUNK_COLS (NROWS / NCHUNK)   // 512
#define CTILES (CHUNK_COLS / BN)      // 4
#define KSTEPS (DDIM / BK)            // 16
#define NBLOCKS ((NROWS / BM) * NCHUNK)  // 1024

typedef float f32x4 __attribute__((ext_vector_type(4)));
typedef short s16x8 __attribute__((ext_vector_type(8)));
typedef __bf16 bf16x8 __attribute__((ext_vector_type(8)));

// ---- MFMA signature hedge: builtin takes either short8 or bf16x8 ----
template <typename V>
__device__ auto mfma_sel(V a, V b, f32x4 c, int)
    -> decltype(__builtin_amdgcn_mfma_f32_16x16x32_bf16(a, b, c, 0, 0, 0)) {
  return __builtin_amdgcn_mfma_f32_16x16x32_bf16(a, b, c, 0, 0, 0);
}
template <typename V>
__device__ f32x4 mfma_sel(V a, V b, f32x4 c, long) {
  return __builtin_amdgcn_mfma_f32_16x16x32_bf16(
      __builtin_bit_cast(bf16x8, a), __builtin_bit_cast(bf16x8, b), c, 0, 0, 0);
}
__device__ inline f32x4 MFMA(s16x8 a, s16x8 b, f32x4 c) {
  return mfma_sel(a, b, c, 0);
}

__device__ inline unsigned short f2bf(float x) {
  unsigned int b = __builtin_bit_cast(unsigned int, x);
  b += 0x7FFFu + ((b >> 16) & 1u);   // RNE
  return (unsigned short)(b >> 16);
}

// ---------------- kernel 1: L2-normalize rows, write bf16 ----------------
__global__ void norm_kernel(const float* __restrict__ in,
                            unsigned short* __restrict__ out) {
  int row = blockIdx.x;
  int t = threadIdx.x;                      // 256 threads
  const float4* r4 = (const float4*)(in + (size_t)row * DDIM);
  float4 v = r4[t];
  float ss = v.x * v.x + v.y * v.y + v.z * v.z + v.w * v.w;
  #pragma unroll
  for (int m = 1; m < 64; m <<= 1) ss += __shfl_xor(ss, m, 64);
  __shared__ float red[4];
  if ((t & 63) == 0) red[t >> 6] = ss;
  __syncthreads();
  float inv = 1.0f / sqrtf(red[0] + red[1] + red[2] + red[3]);
  ushort4 o;
  o.x = f2bf(v.x * inv); o.y = f2bf(v.y * inv);
  o.z = f2bf(v.z * inv); o.w = f2bf(v.w * inv);
  ((ushort4*)(out + (size_t)row * DDIM))[t] = o;
}

// ---- staging: linear LDS dest (global_load_lds), swizzled global source ---
// LDS tile layout: 128 rows x 128 bytes; 16B slot s of row r holds
// k-elements c*8..c*8+7 where c = s ^ (r&7).  Read applies the same XOR.
__device__ inline void stage_tile(const unsigned short* __restrict__ f,
                                  unsigned short* lds, int row0, int kbase,
                                  int w, int lane) {
  #pragma unroll
  for (int i = 0; i < 4; ++i) {
    int q = w * 4 + i;                 // 16 wave-issues of 1024B per tile
    int r = q * 8 + (lane >> 3);
    int slot = lane & 7;
    int c = slot ^ (r & 7);
    const unsigned short* g = f + (size_t)(row0 + r) * DDIM + kbase + c * 8;
    __builtin_amdgcn_global_load_lds(
        (const __attribute__((address_space(1))) void*)g,
        (__attribute__((address_space(3))) void*)(lds + q * 512), 16, 0, 0);
  }
}

// ---------------- kernel 2: fused sim GEMM + fixed-max expsum -------------
__global__ __launch_bounds__(256, 4)
void simloss_kernel(const unsigned short* __restrict__ f,
                    float* __restrict__ s_part,
                    float* __restrict__ pos_out) {
  __shared__ __align__(16) unsigned short As[BM * BK];  // 16 KB
  __shared__ __align__(16) unsigned short Bs[BN * BK];  // 16 KB

  // XCD-aware swizzle: 1024 blocks % 8 == 0 -> bijective simple form.
  int bid = blockIdx.x;
  int orig = (bid & 7) * (NBLOCKS / 8) + (bid >> 3);
  int rt = orig >> 4;          // 64 row tiles
  int ch = orig & 15;          // 16 col chunks
  int rowBase = rt * BM;
  int chunkBase = ch * CHUNK_COLS;

  int tid = threadIdx.x;
  int lane = tid & 63;
  int w = tid >> 6;        // 4 waves
  int wm = w >> 1, wn = w & 1;

  float s_run[16];
  #pragma unroll
  for (int i = 0; i < 16; ++i) s_run[i] = 0.f;

  for (int ct = 0; ct < CTILES; ++ct) {
    int colBase = chunkBase + ct * BN;
    f32x4 acc[4][4];
    #pragma unroll
    for (int i = 0; i < 4; ++i)
      #pragma unroll
      for (int j = 0; j < 4; ++j) acc[i][j] = (f32x4){0.f, 0.f, 0.f, 0.f};

    for (int kt = 0; kt < KSTEPS; ++kt) {
      __syncthreads();                       // prior reads of As/Bs done
      stage_tile(f, As, rowBase, kt * BK, w, lane);
      stage_tile(f, Bs, colBase, kt * BK, w, lane);
      __syncthreads();                       // staged data visible

      #pragma unroll
      for (int kk = 0; kk < 2; ++kk) {       // two K=32 sub-steps of BK=64
        int cs = (lane >> 4) + kk * 4;       // 16B slot index of k-elems
        s16x8 b[4];
        #pragma unroll
        for (int fn = 0; fn < 4; ++fn) {
          int r = wn * 64 + fn * 16 + (lane & 15);
          b[fn] = *(const s16x8*)((const char*)Bs + r * 128 + ((cs ^ (r & 7)) << 4));
        }
        #pragma unroll
        for (int fm = 0; fm < 4; ++fm) {
          int r = wm * 64 + fm * 16 + (lane & 15);
          s16x8 a = *(const s16x8*)((const char*)As + r * 128 + ((cs ^ (r & 7)) << 4));
          #pragma unroll
          for (int fn = 0; fn < 4; ++fn)
            acc[fm][fn] = MFMA(a, b[fn], acc[fm][fn]);
        }
      }
    }

    // epilogue: s += exp(x - M0), x = acc*ISCALE, M0 = ISCALE (exact max:
    // unit rows => sim <= 1). Self-mask / positive only in 2 special tiles.
    bool hasDiag = (colBase == rowBase);
    bool hasPos  = (colBase == (rowBase ^ BHALF));
    if (hasDiag | hasPos) {
      #pragma unroll
      for (int fm = 0; fm < 4; ++fm) {
        #pragma unroll
        for (int j = 0; j < 4; ++j) {
          int R = rowBase + wm * 64 + fm * 16 + ((lane >> 4) << 2) + j;
          #pragma unroll
          for (int fn = 0; fn < 4; ++fn) {
            int C = colBase + wn * 64 + fn * 16 + (lane & 15);
            float x = acc[fm][fn][j] * ISCALE;
            float e = __expf(x - ISCALE);
            if (C == R) e = 0.f;                       // self-mask
            if (C == (R ^ BHALF)) pos_out[R] = x;      // positive capture
            s_run[fm * 4 + j] += e;
          }
        }
      }
    } else {
      #pragma unroll
      for (int fm = 0; fm < 4; ++fm)
        #pragma unroll
        for (int j = 0; j < 4; ++j)
          #pragma unroll
          for (int fn = 0; fn < 4; ++fn)
            s_run[fm * 4 + j] +=
                __expf(fmaf(acc[fm][fn][j], ISCALE, -ISCALE));
    }
  }

  // once-per-kernel cross-lane reduce (cols live in lane&15) and write.
  #pragma unroll
  for (int fm = 0; fm < 4; ++fm) {
    #pragma unroll
    for (int j = 0; j < 4; ++j) {
      float s = s_run[fm * 4 + j];
      s += __shfl_xor(s, 1, 64);
      s += __shfl_xor(s, 2, 64);
      s += __shfl_xor(s, 4, 64);
      s += __shfl_xor(s, 8, 64);
      if ((lane & 15) == 0) {
        int R = rowBase + wm * 64 + fm * 16 + ((lane >> 4) << 2) + j;
        s_part[(size_t)R * (NCHUNK * 2) + ch * 2 + wn] = s;
      }
    }
  }
}

// ---------------- kernel 3a: per-row loss, 64-block partial sums ----------
__global__ void finalize1_kernel(const float* __restrict__ s_part,
                                 const float* __restrict__ pos,
                                 float* __restrict__ part2) {
  int r = blockIdx.x * 128 + threadIdx.x;   // 64 blocks x 128 threads
  float S = 0.f;
  #pragma unroll
  for (int k = 0; k < NCHUNK * 2; ++k) S += s_part[(size_t)r * (NCHUNK * 2) + k];
  float local = (ISCALE + logf(S)) - pos[r];
  #pragma unroll
  for (int m = 1; m < 64; m <<= 1) local += __shfl_xor(local, m, 64);
  __shared__ float red[2];
  if ((threadIdx.x & 63) == 0) red[threadIdx.x >> 6] = local;
  __syncthreads();
  if (threadIdx.x == 0) part2[blockIdx.x] = red[0] + red[1];
}

// ---------------- kernel 3b: merge 64 partials, mean ----------------------
__global__ void finalize2_kernel(const float* __restrict__ part2,
                                 float* __restrict__ out) {
  float v = part2[threadIdx.x];             // 64 threads
  #pragma unroll
  for (int m = 1; m < 64; m <<= 1) v += __shfl_xor(v, m, 64);
  if (threadIdx.x == 0) out[0] = v / (float)NROWS;
}

extern "C" void kernel_launch(void* const* d_in, const int* in_sizes, int n_in,
                              void* d_out, int out_size, void* d_ws,
                              size_t ws_size, hipStream_t stream) {
  const float* feats = (const float*)d_in[0];
  char* ws = (char*)d_ws;
  unsigned short* fbf = (unsigned short*)ws;                      // 16 MB
  float* s_part = (float*)(ws + (size_t)NROWS * DDIM * 2);        // 1 MB
  float* pos    = (float*)((char*)s_part + (size_t)NROWS * NCHUNK * 2 * 4);
  float* part2  = (float*)((char*)pos + (size_t)NROWS * 4);
  float* out = (float*)d_out;

  norm_kernel<<<NROWS, 256, 0, stream>>>(feats, fbf);
  simloss_kernel<<<NBLOCKS, 256, 0, stream>>>(fbf, s_part, pos);
  finalize1_kernel<<<64, 128, 0, stream>>>(s_part, pos, part2);
  finalize2_kernel<<<1, 64, 0, stream>>>(part2, out);
}

// Round 3
// 214.214 us; speedup vs baseline: 2.1568x; 1.0154x over previous
//
#include <hip/hip_runtime.h>
#include <hip/hip_bf16.h>

// NT-Xent / InfoNCE loss. features [8192,1024] fp32 -> scalar fp32.
// normalize->bf16, fused MFMA GEMM (f f^T / T) + fixed-max logsumexp,
// 2-phase double-buffered LDS pipeline (stage t+1 before compute t).

#define NROWS 8192
#define DDIM  1024
#define BHALF 4096            // positive index = row ^ BHALF
#define ISCALE 14.2857142857142857f  // 1/0.07 == fixed logsumexp max M0

#define BM 128
#define BN 128
#define BK 64
#define NCHUNK 16
#define CHUNK_COLS (NROWS / NCHUNK)   // 512
#define CTILES (CHUNK_COLS / BN)      // 4
#define KSTEPS (DDIM / BK)            // 16
#define NSTEPS (CTILES * KSTEPS)      // 64 linear (ct,kt) steps
#define NBLOCKS ((NROWS / BM) * NCHUNK)  // 1024 = 2 blocks/CU exactly

typedef float f32x4 __attribute__((ext_vector_type(4)));
typedef short s16x8 __attribute__((ext_vector_type(8)));
typedef __bf16 bf16x8 __attribute__((ext_vector_type(8)));

// ---- MFMA signature hedge: builtin takes either short8 or bf16x8 ----
template <typename V>
__device__ auto mfma_sel(V a, V b, f32x4 c, int)
    -> decltype(__builtin_amdgcn_mfma_f32_16x16x32_bf16(a, b, c, 0, 0, 0)) {
  return __builtin_amdgcn_mfma_f32_16x16x32_bf16(a, b, c, 0, 0, 0);
}
template <typename V>
__device__ f32x4 mfma_sel(V a, V b, f32x4 c, long) {
  return __builtin_amdgcn_mfma_f32_16x16x32_bf16(
      __builtin_bit_cast(bf16x8, a), __builtin_bit_cast(bf16x8, b), c, 0, 0, 0);
}
__device__ inline f32x4 MFMA(s16x8 a, s16x8 b, f32x4 c) {
  return mfma_sel(a, b, c, 0);
}

__device__ inline unsigned short f2bf(float x) {
  unsigned int b = __builtin_bit_cast(unsigned int, x);
  b += 0x7FFFu + ((b >> 16) & 1u);   // RNE
  return (unsigned short)(b >> 16);
}

// ------------- kernel 1: L2-normalize rows, wave-per-row, no LDS ---------
__global__ __launch_bounds__(256)
void norm_kernel(const float* __restrict__ in, unsigned short* __restrict__ out) {
  int row = blockIdx.x * 4 + (threadIdx.x >> 6);   // 2048 blocks x 4 waves
  int lane = threadIdx.x & 63;
  const float4* r4 = (const float4*)(in + (size_t)row * DDIM);
  float4 v0 = r4[lane], v1 = r4[lane + 64], v2 = r4[lane + 128],
         v3 = r4[lane + 192];
  float ss = v0.x * v0.x + v0.y * v0.y + v0.z * v0.z + v0.w * v0.w +
             v1.x * v1.x + v1.y * v1.y + v1.z * v1.z + v1.w * v1.w +
             v2.x * v2.x + v2.y * v2.y + v2.z * v2.z + v2.w * v2.w +
             v3.x * v3.x + v3.y * v3.y + v3.z * v3.z + v3.w * v3.w;
  #pragma unroll
  for (int m = 1; m < 64; m <<= 1) ss += __shfl_xor(ss, m, 64);
  float inv = 1.0f / sqrtf(ss);
  ushort4* o4 = (ushort4*)(out + (size_t)row * DDIM);
  ushort4 o;
  o.x = f2bf(v0.x * inv); o.y = f2bf(v0.y * inv);
  o.z = f2bf(v0.z * inv); o.w = f2bf(v0.w * inv); o4[lane] = o;
  o.x = f2bf(v1.x * inv); o.y = f2bf(v1.y * inv);
  o.z = f2bf(v1.z * inv); o.w = f2bf(v1.w * inv); o4[lane + 64] = o;
  o.x = f2bf(v2.x * inv); o.y = f2bf(v2.y * inv);
  o.z = f2bf(v2.z * inv); o.w = f2bf(v2.w * inv); o4[lane + 128] = o;
  o.x = f2bf(v3.x * inv); o.y = f2bf(v3.y * inv);
  o.z = f2bf(v3.z * inv); o.w = f2bf(v3.w * inv); o4[lane + 192] = o;
}

// ---- staging: linear LDS dest (global_load_lds), swizzled global source ---
// LDS tile layout: 128 rows x 128 bytes; 16B slot s of row r holds
// k-elements c*8..c*8+7 where c = s ^ (r&7).  Read applies the same XOR.
__device__ inline void stage_tile(const unsigned short* __restrict__ f,
                                  unsigned short* lds, int row0, int kbase,
                                  int w, int lane) {
  #pragma unroll
  for (int i = 0; i < 4; ++i) {
    int q = w * 4 + i;                 // 16 wave-issues of 1024B per tile
    int r = q * 8 + (lane >> 3);
    int slot = lane & 7;
    int c = slot ^ (r & 7);
    const unsigned short* g = f + (size_t)(row0 + r) * DDIM + kbase + c * 8;
    __builtin_amdgcn_global_load_lds(
        (const __attribute__((address_space(1))) void*)g,
        (__attribute__((address_space(3))) void*)(lds + q * 512), 16, 0, 0);
  }
}

// ---------------- kernel 2: fused sim GEMM + fixed-max expsum -------------
__global__ __launch_bounds__(256, 2)
void simloss_kernel(const unsigned short* __restrict__ f,
                    float* __restrict__ s_part,
                    float* __restrict__ pos_out) {
  __shared__ __align__(16) unsigned short As[2][BM * BK];  // 2 x 16 KB
  __shared__ __align__(16) unsigned short Bs[2][BN * BK];  // 2 x 16 KB

  // XCD-aware swizzle: 1024 blocks % 8 == 0 -> bijective simple form.
  int bid = blockIdx.x;
  int orig = (bid & 7) * (NBLOCKS / 8) + (bid >> 3);
  int rt = orig >> 4;          // 64 row tiles
  int ch = orig & 15;          // 16 col chunks
  int rowBase = rt * BM;
  int chunkBase = ch * CHUNK_COLS;

  int tid = threadIdx.x;
  int lane = tid & 63;
  int w = tid >> 6;        // 4 waves
  int wm = w >> 1, wn = w & 1;

  float s_run[16];
  #pragma unroll
  for (int i = 0; i < 16; ++i) s_run[i] = 0.f;

  f32x4 acc[4][4];
  #pragma unroll
  for (int i = 0; i < 4; ++i)
    #pragma unroll
    for (int j = 0; j < 4; ++j) acc[i][j] = (f32x4){0.f, 0.f, 0.f, 0.f};

  // prologue: stage step 0 into buf0, drain, barrier
  stage_tile(f, As[0], rowBase, 0, w, lane);
  stage_tile(f, Bs[0], chunkBase, 0, w, lane);
  __syncthreads();   // vmcnt(0) drain + barrier

  for (int g = 0; g < NSTEPS; ++g) {
    int ct = g >> 4;
    int cur = g & 1;

    // ---- issue next-step stage into the other buffer (flies under compute)
    if (g + 1 < NSTEPS) {
      int g2 = g + 1;
      stage_tile(f, As[g2 & 1], rowBase, (g2 & 15) * BK, w, lane);
      stage_tile(f, Bs[g2 & 1], chunkBase + (g2 >> 4) * BN, (g2 & 15) * BK,
                 w, lane);
    }

    // ---- compute current K-step from buf[cur]
    #pragma unroll
    for (int kk = 0; kk < 2; ++kk) {       // two K=32 sub-steps of BK=64
      int cs = (lane >> 4) + kk * 4;       // 16B slot index of k-elems
      s16x8 b[4];
      #pragma unroll
      for (int fn = 0; fn < 4; ++fn) {
        int r = wn * 64 + fn * 16 + (lane & 15);
        b[fn] = *(const s16x8*)((const char*)Bs[cur] + r * 128 +
                                ((cs ^ (r & 7)) << 4));
      }
      #pragma unroll
      for (int fm = 0; fm < 4; ++fm) {
        int r = wm * 64 + fm * 16 + (lane & 15);
        s16x8 a = *(const s16x8*)((const char*)As[cur] + r * 128 +
                                  ((cs ^ (r & 7)) << 4));
        #pragma unroll
        for (int fn = 0; fn < 4; ++fn)
          acc[fm][fn] = MFMA(a, b[fn], acc[fm][fn]);
      }
    }

    // ---- epilogue at the last K-step of each col-tile (registers only)
    if ((g & 15) == 15) {
      int colBase = chunkBase + ct * BN;
      bool hasDiag = (colBase == rowBase);
      bool hasPos  = (colBase == (rowBase ^ BHALF));
      if (hasDiag | hasPos) {
        #pragma unroll
        for (int fm = 0; fm < 4; ++fm) {
          #pragma unroll
          for (int j = 0; j < 4; ++j) {
            int R = rowBase + wm * 64 + fm * 16 + ((lane >> 4) << 2) + j;
            #pragma unroll
            for (int fn = 0; fn < 4; ++fn) {
              int C = colBase + wn * 64 + fn * 16 + (lane & 15);
              float x = acc[fm][fn][j] * ISCALE;
              float e = __expf(x - ISCALE);
              if (C == R) e = 0.f;                       // self-mask
              if (C == (R ^ BHALF)) pos_out[R] = x;      // positive capture
              s_run[fm * 4 + j] += e;
            }
          }
        }
      } else {
        #pragma unroll
        for (int fm = 0; fm < 4; ++fm)
          #pragma unroll
          for (int j = 0; j < 4; ++j)
            #pragma unroll
            for (int fn = 0; fn < 4; ++fn)
              s_run[fm * 4 + j] +=
                  __expf(fmaf(acc[fm][fn][j], ISCALE, -ISCALE));
      }
      #pragma unroll
      for (int i = 0; i < 4; ++i)
        #pragma unroll
        for (int j = 0; j < 4; ++j) acc[i][j] = (f32x4){0.f, 0.f, 0.f, 0.f};
    }

    __syncthreads();   // vmcnt(0)+lgkmcnt(0) drain + barrier, once per step
  }

  // once-per-kernel cross-lane reduce (cols live in lane&15) and write.
  #pragma unroll
  for (int fm = 0; fm < 4; ++fm) {
    #pragma unroll
    for (int j = 0; j < 4; ++j) {
      float s = s_run[fm * 4 + j];
      s += __shfl_xor(s, 1, 64);
      s += __shfl_xor(s, 2, 64);
      s += __shfl_xor(s, 4, 64);
      s += __shfl_xor(s, 8, 64);
      if ((lane & 15) == 0) {
        int R = rowBase + wm * 64 + fm * 16 + ((lane >> 4) << 2) + j;
        s_part[(size_t)R * (NCHUNK * 2) + ch * 2 + wn] = s;
      }
    }
  }
}

// ---------------- kernel 3a: per-row loss, 64-block partial sums ----------
__global__ void finalize1_kernel(const float* __restrict__ s_part,
                                 const float* __restrict__ pos,
                                 float* __restrict__ part2) {
  int r = blockIdx.x * 128 + threadIdx.x;   // 64 blocks x 128 threads
  float S = 0.f;
  #pragma unroll
  for (int k = 0; k < NCHUNK * 2; ++k) S += s_part[(size_t)r * (NCHUNK * 2) + k];
  float local = (ISCALE + logf(S)) - pos[r];
  #pragma unroll
  for (int m = 1; m < 64; m <<= 1) local += __shfl_xor(local, m, 64);
  __shared__ float red[2];
  if ((threadIdx.x & 63) == 0) red[threadIdx.x >> 6] = local;
  __syncthreads();
  if (threadIdx.x == 0) part2[blockIdx.x] = red[0] + red[1];
}

// ---------------- kernel 3b: merge 64 partials, mean ----------------------
__global__ void finalize2_kernel(const float* __restrict__ part2,
                                 float* __restrict__ out) {
  float v = part2[threadIdx.x];             // 64 threads
  #pragma unroll
  for (int m = 1; m < 64; m <<= 1) v += __shfl_xor(v, m, 64);
  if (threadIdx.x == 0) out[0] = v / (float)NROWS;
}

extern "C" void kernel_launch(void* const* d_in, const int* in_sizes, int n_in,
                              void* d_out, int out_size, void* d_ws,
                              size_t ws_size, hipStream_t stream) {
  const float* feats = (const float*)d_in[0];
  char* ws = (char*)d_ws;
  unsigned short* fbf = (unsigned short*)ws;                      // 16 MB
  float* s_part = (float*)(ws + (size_t)NROWS * DDIM * 2);        // 1 MB
  float* pos    = (float*)((char*)s_part + (size_t)NROWS * NCHUNK * 2 * 4);
  float* part2  = (float*)((char*)pos + (size_t)NROWS * 4);
  float* out = (float*)d_out;

  norm_kernel<<<NROWS / 4, 256, 0, stream>>>(feats, fbf);
  simloss_kernel<<<NBLOCKS, 256, 0, stream>>>(fbf, s_part, pos);
  finalize1_kernel<<<64, 128, 0, stream>>>(s_part, pos, part2);
  finalize2_kernel<<<1, 64, 0, stream>>>(part2, out);
}

// Round 5
// 172.357 us; speedup vs baseline: 2.6806x; 1.2429x over previous
//
#include <hip/hip_runtime.h>
#include <hip/hip_bf16.h>

// NT-Xent / InfoNCE loss. features [8192,1024] fp32 -> scalar fp32.
// normalize->bf16, then SYMMETRIC fused MFMA GEMM: sim = f f^T is symmetric,
// so only upper-triangle 128x128 tiles are computed (2080 of 4096). Each
// off-diag tile contributes exp-sums to its rows (row-sums) AND its cols
// (col-sums, = transposed rows). Fixed-max logsumexp (unit rows => sim<=1).
// Denominators accumulate via fp32 atomics.

#define NROWS 8192
#define DDIM  1024
#define BHALF 4096            // positive index = row ^ BHALF
#define ISCALE 14.2857142857142857f  // 1/0.07 == fixed logsumexp max M0

#define BM 128
#define BN 128
#define BK 64
#define KSTEPS (DDIM / BK)            // 16
#define TGRID (NROWS / BM)            // 64
#define NTILES (TGRID * (TGRID + 1) / 2)  // 2080 upper-triangle tiles

typedef float f32x4 __attribute__((ext_vector_type(4)));
typedef short s16x8 __attribute__((ext_vector_type(8)));
typedef __bf16 bf16x8 __attribute__((ext_vector_type(8)));

// ---- MFMA signature hedge: builtin takes either short8 or bf16x8 ----
template <typename V>
__device__ auto mfma_sel(V a, V b, f32x4 c, int)
    -> decltype(__builtin_amdgcn_mfma_f32_16x16x32_bf16(a, b, c, 0, 0, 0)) {
  return __builtin_amdgcn_mfma_f32_16x16x32_bf16(a, b, c, 0, 0, 0);
}
template <typename V>
__device__ f32x4 mfma_sel(V a, V b, f32x4 c, long) {
  return __builtin_amdgcn_mfma_f32_16x16x32_bf16(
      __builtin_bit_cast(bf16x8, a), __builtin_bit_cast(bf16x8, b), c, 0, 0, 0);
}
__device__ inline f32x4 MFMA(s16x8 a, s16x8 b, f32x4 c) {
  return mfma_sel(a, b, c, 0);
}

__device__ inline unsigned short f2bf(float x) {
  unsigned int b = __builtin_bit_cast(unsigned int, x);
  b += 0x7FFFu + ((b >> 16) & 1u);   // RNE
  return (unsigned short)(b >> 16);
}

// ------------- kernel 1: L2-normalize rows (wave-per-row) + zero s_accum --
__global__ __launch_bounds__(256)
void norm_kernel(const float* __restrict__ in, unsigned short* __restrict__ out,
                 float* __restrict__ s_accum) {
  int gid = blockIdx.x * 256 + threadIdx.x;
  if (gid < NROWS) s_accum[gid] = 0.f;     // zero denominators for atomics

  int row = blockIdx.x * 4 + (threadIdx.x >> 6);   // 2048 blocks x 4 waves
  int lane = threadIdx.x & 63;
  const float4* r4 = (const float4*)(in + (size_t)row * DDIM);
  float4 v0 = r4[lane], v1 = r4[lane + 64], v2 = r4[lane + 128],
         v3 = r4[lane + 192];
  float ss = v0.x * v0.x + v0.y * v0.y + v0.z * v0.z + v0.w * v0.w +
             v1.x * v1.x + v1.y * v1.y + v1.z * v1.z + v1.w * v1.w +
             v2.x * v2.x + v2.y * v2.y + v2.z * v2.z + v2.w * v2.w +
             v3.x * v3.x + v3.y * v3.y + v3.z * v3.z + v3.w * v3.w;
  #pragma unroll
  for (int m = 1; m < 64; m <<= 1) ss += __shfl_xor(ss, m, 64);
  float inv = 1.0f / sqrtf(ss);
  ushort4* o4 = (ushort4*)(out + (size_t)row * DDIM);
  ushort4 o;
  o.x = f2bf(v0.x * inv); o.y = f2bf(v0.y * inv);
  o.z = f2bf(v0.z * inv); o.w = f2bf(v0.w * inv); o4[lane] = o;
  o.x = f2bf(v1.x * inv); o.y = f2bf(v1.y * inv);
  o.z = f2bf(v1.z * inv); o.w = f2bf(v1.w * inv); o4[lane + 64] = o;
  o.x = f2bf(v2.x * inv); o.y = f2bf(v2.y * inv);
  o.z = f2bf(v2.z * inv); o.w = f2bf(v2.w * inv); o4[lane + 128] = o;
  o.x = f2bf(v3.x * inv); o.y = f2bf(v3.y * inv);
  o.z = f2bf(v3.z * inv); o.w = f2bf(v3.w * inv); o4[lane + 192] = o;
}

// ---- staging: linear LDS dest (global_load_lds), swizzled global source ---
// LDS tile layout: 128 rows x 128 bytes; 16B slot s of row r holds
// k-elements c*8..c*8+7 where c = s ^ (r&7).  Read applies the same XOR.
__device__ inline void stage_tile(const unsigned short* __restrict__ f,
                                  unsigned short* lds, int row0, int kbase,
                                  int w, int lane) {
  #pragma unroll
  for (int i = 0; i < 4; ++i) {
    int q = w * 4 + i;                 // 16 wave-issues of 1024B per tile
    int r = q * 8 + (lane >> 3);
    int slot = lane & 7;
    int c = slot ^ (r & 7);
    const unsigned short* g = f + (size_t)(row0 + r) * DDIM + kbase + c * 8;
    __builtin_amdgcn_global_load_lds(
        (const __attribute__((address_space(1))) void*)g,
        (__attribute__((address_space(3))) void*)(lds + q * 512), 16, 0, 0);
  }
}

// ------- kernel 2: upper-triangle fused sim GEMM + fixed-max expsum -------
__global__ __launch_bounds__(256, 4)
void simloss_kernel(const unsigned short* __restrict__ f,
                    float* __restrict__ s_accum,
                    float* __restrict__ pos_out) {
  __shared__ __align__(16) unsigned short As[BM * BK];  // 16 KB
  __shared__ __align__(16) unsigned short Bs[BN * BK];  // 16 KB

  // XCD-aware swizzle: 2080 % 8 == 0 -> simple bijective form.
  int bid = blockIdx.x;
  int b = (bid & 7) * (NTILES / 8) + (bid >> 3);
  // triangle decode: tiles enumerated rt=0..63, ct=rt..63;
  // tiles before row rt: C(rt) = rt*(129-rt)/2.
  int rt = (int)((129.0 - sqrt(129.0 * 129.0 - 8.0 * (double)b)) * 0.5);
  while ((rt + 1) * (129 - (rt + 1)) / 2 <= b) ++rt;
  while (rt * (129 - rt) / 2 > b) --rt;
  int ct = rt + (b - rt * (129 - rt) / 2);
  int rowBase = rt * BM;
  int colBase = ct * BN;
  bool isDiag = (rt == ct);
  bool hasPos = (colBase == (rowBase ^ BHALF));

  int tid = threadIdx.x;
  int lane = tid & 63;
  int w = tid >> 6;        // 4 waves
  int wm = w >> 1, wn = w & 1;

  f32x4 acc[4][4];
  #pragma unroll
  for (int i = 0; i < 4; ++i)
    #pragma unroll
    for (int j = 0; j < 4; ++j) acc[i][j] = (f32x4){0.f, 0.f, 0.f, 0.f};

  for (int kt = 0; kt < KSTEPS; ++kt) {
    __syncthreads();                       // prior reads of As/Bs done
    stage_tile(f, As, rowBase, kt * BK, w, lane);
    stage_tile(f, Bs, colBase, kt * BK, w, lane);
    __syncthreads();                       // staged data visible

    #pragma unroll
    for (int kk = 0; kk < 2; ++kk) {       // two K=32 sub-steps of BK=64
      int cs = (lane >> 4) + kk * 4;       // 16B slot index of k-elems
      s16x8 bfr[4];
      #pragma unroll
      for (int fn = 0; fn < 4; ++fn) {
        int r = wn * 64 + fn * 16 + (lane & 15);
        bfr[fn] = *(const s16x8*)((const char*)Bs + r * 128 +
                                  ((cs ^ (r & 7)) << 4));
      }
      #pragma unroll
      for (int fm = 0; fm < 4; ++fm) {
        int r = wm * 64 + fm * 16 + (lane & 15);
        s16x8 a = *(const s16x8*)((const char*)As + r * 128 +
                                  ((cs ^ (r & 7)) << 4));
        #pragma unroll
        for (int fn = 0; fn < 4; ++fn)
          acc[fm][fn] = MFMA(a, bfr[fn], acc[fm][fn]);
      }
    }
  }

  // epilogue: e = exp(x - M0); accumulate row-sums and (off-diag) col-sums.
  float s_row[16], s_col[4];
  #pragma unroll
  for (int i = 0; i < 16; ++i) s_row[i] = 0.f;
  #pragma unroll
  for (int i = 0; i < 4; ++i) s_col[i] = 0.f;

  if (isDiag | hasPos) {
    #pragma unroll
    for (int fm = 0; fm < 4; ++fm) {
      #pragma unroll
      for (int j = 0; j < 4; ++j) {
        int R = rowBase + wm * 64 + fm * 16 + ((lane >> 4) << 2) + j;
        #pragma unroll
        for (int fn = 0; fn < 4; ++fn) {
          int C = colBase + wn * 64 + fn * 16 + (lane & 15);
          float x = acc[fm][fn][j] * ISCALE;
          float e = __expf(x - ISCALE);
          if (C == R) e = 0.f;                        // self-mask (diag only)
          if (hasPos && C == (R ^ BHALF)) {           // positive capture
            pos_out[R] = x;                           // sim[R][C]
            pos_out[C] = x;                           // sim[C][R] == sim[R][C]
          }
          s_row[fm * 4 + j] += e;
          s_col[fn] += e;
        }
      }
    }
  } else {
    #pragma unroll
    for (int fm = 0; fm < 4; ++fm) {
      #pragma unroll
      for (int j = 0; j < 4; ++j) {
        #pragma unroll
        for (int fn = 0; fn < 4; ++fn) {
          float e = __expf(fmaf(acc[fm][fn][j], ISCALE, -ISCALE));
          s_row[fm * 4 + j] += e;
          s_col[fn] += e;
        }
      }
    }
  }

  // row-sums: reduce across cols (lane&15), one atomic per row per wave.
  #pragma unroll
  for (int fm = 0; fm < 4; ++fm) {
    #pragma unroll
    for (int j = 0; j < 4; ++j) {
      float s = s_row[fm * 4 + j];
      s += __shfl_xor(s, 1, 64);
      s += __shfl_xor(s, 2, 64);
      s += __shfl_xor(s, 4, 64);
      s += __shfl_xor(s, 8, 64);
      if ((lane & 15) == 0) {
        int R = rowBase + wm * 64 + fm * 16 + ((lane >> 4) << 2) + j;
        atomicAdd(&s_accum[R], s);
      }
    }
  }
  // col-sums: reduce across rows (lane>>4), skip on diagonal tiles
  // (diag tile already holds both (i,j) and (j,i) in its row-sums).
  if (!isDiag) {
    #pragma unroll
    for (int fn = 0; fn < 4; ++fn) {
      float c = s_col[fn];
      c += __shfl_xor(c, 16, 64);
      c += __shfl_xor(c, 32, 64);
      if (lane < 16) {
        int C = colBase + wn * 64 + fn * 16 + lane;
        atomicAdd(&s_accum[C], c);
      }
    }
  }
}

// ---------------- kernel 3a: per-row loss, 64-block partial sums ----------
__global__ void finalize1_kernel(const float* __restrict__ s_accum,
                                 const float* __restrict__ pos,
                                 float* __restrict__ part2) {
  int r = blockIdx.x * 128 + threadIdx.x;   // 64 blocks x 128 threads
  float local = (ISCALE + logf(s_accum[r])) - pos[r];
  #pragma unroll
  for (int m = 1; m < 64; m <<= 1) local += __shfl_xor(local, m, 64);
  __shared__ float red[2];
  if ((threadIdx.x & 63) == 0) red[threadIdx.x >> 6] = local;
  __syncthreads();
  if (threadIdx.x == 0) part2[blockIdx.x] = red[0] + red[1];
}

// ---------------- kernel 3b: merge 64 partials, mean ----------------------
__global__ void finalize2_kernel(const float* __restrict__ part2,
                                 float* __restrict__ out) {
  float v = part2[threadIdx.x];             // 64 threads
  #pragma unroll
  for (int m = 1; m < 64; m <<= 1) v += __shfl_xor(v, m, 64);
  if (threadIdx.x == 0) out[0] = v / (float)NROWS;
}

extern "C" void kernel_launch(void* const* d_in, const int* in_sizes, int n_in,
                              void* d_out, int out_size, void* d_ws,
                              size_t ws_size, hipStream_t stream) {
  const float* feats = (const float*)d_in[0];
  char* ws = (char*)d_ws;
  unsigned short* fbf = (unsigned short*)ws;                      // 16 MB
  float* s_accum = (float*)(ws + (size_t)NROWS * DDIM * 2);       // 32 KB
  float* pos     = (float*)((char*)s_accum + (size_t)NROWS * 4);
  float* part2   = (float*)((char*)pos + (size_t)NROWS * 4);
  float* out = (float*)d_out;

  norm_kernel<<<NROWS / 4, 256, 0, stream>>>(feats, fbf, s_accum);
  simloss_kernel<<<NTILES, 256, 0, stream>>>(fbf, s_accum, pos);
  finalize1_kernel<<<64, 128, 0, stream>>>(s_accum, pos, part2);
  finalize2_kernel<<<1, 64, 0, stream>>>(part2, out);
}